// Round 15
// baseline (8749.491 us; speedup 1.0000x reference)
//
#include <hip/hip_runtime.h>
#include <math.h>

// Echo-state network: sequential scan with dense 2048x2048 matvec per step.
// R15 -- R14 structure; rounds 4864 -> 4288 (warm-up 1024 -> 256) + x-load
// software-pipelined one round:
//  - Register-pool arithmetic (R12 post-mortem, confirmed by R14 fit):
//    pool ~512 regs/lane-slot/SIMD; this kernel uses ~236/wave -> exactly
//    2 waves/SIMD. 4 chunks is the hard cap for W-in-register replication.
//  - Warm-up: contraction lambda ~ 0.5 + 0.5*rho*E[sech^2(u)] ~ 0.87/step
//    (u std ~0.6); needed lambda^W < 1.3e-3 -> W >= 48. WUP=256 gives e^-36
//    margin (WUP 2048->1024 was bit-identical in absmax). Uneven chunks
//    equalize finish: chunk0 = 4288 outputs, chunks1-3 = 4032 + 256 warm-up
//    -> uniform 4288 rounds. Boundaries 4288/8320/12352 (%16==0).
//  - x pipeline: x[g+1] issued AFTER the barrier (carried in a register, NO
//    asm pin -- R6's pin forced a waitcnt at the pin site and regressed).
//    Its latency hides under consume; next round's first drain finds it
//    already arrived.
//  - XCD-affinity remap: chunk = (blk&7)>>1 -> chunk's 64 blocks on XCD pair
//    {2c,2c+1} under blockIdx%8 round-robin dispatch (R14, kept).
//  - Parity bias-tag: even chunks store h+2, odd h+6; poll accepts
//    |v-bias|<=1.25; memset-0 / 0xAA poison read not-ready. Warm-up writes
//    of chunk c+1 trail chunk c's true writes by ~4000 lockstep rounds.
//  - Per-round machinery = R5/R11: block-cooperative poll (4 dwords/thr),
//    straggler-only retry, publish to LDS, ONE barrier, consume
//    8 x ds_read_b128 vs register W, 7-shfl reduce, tanh, store.
//  - fc1/fc2 collapse: out = states_biased @ Mt + (c2b - bias_t * rm).

#define SS 16384
#define II 64
#define RR 2048
#define HH 128
#define OO 50
#define OP 64          // padded output dim
#define NROUND 4288    // rounds per chunk (uniform)
#define C0LEN 4288     // chunk 0 output length
#define CLEN 4032      // chunks 1-3 output length
#define WUP 256        // warm-up steps for chunks 1-3
#define NBLK 256
#define NTHR 512
#define TT 16          // timesteps per block in out_kernel

static const size_t STATES_BYTES = (size_t)SS * RR * 4;        // 134217728
static const size_t MT_OFF  = STATES_BYTES;
static const size_t C2B_OFF = MT_OFF + (size_t)RR * OP * 4;    // +524288
static const size_t RM_OFF  = C2B_OFF + 256;
static const size_t RS_OFF  = RM_OFF + 256;
static const size_t WS_NEED = RS_OFF + 512 + 256;

// Opaque register pin for LOOP-INVARIANT values (W fragments) only.
// NEVER on in-loop load results (forces a waitcnt at the pin site -- R6).
#define PIN4(q) asm volatile("" : "+v"((q).x), "+v"((q).y), "+v"((q).z), "+v"((q).w))

// ---------------------------------------------------------------------------
// Persistent chunked scan. chunk = (blk&7)>>1 (XCD-pair affinity),
// brow = (blk>>3)*2 + (blk&1). Wave w owns rows R0=brow*32+w*4 .. R0+3;
// lane l holds cols {4l+j+256m} of its 4 rows.
// ---------------------------------------------------------------------------
__global__ __launch_bounds__(NTHR, 2)
void scan_kernel(const float* __restrict__ x,
                 const float* __restrict__ Win,
                 const float* __restrict__ W,
                 float* __restrict__ states)
{
    const int tid   = threadIdx.x;
    const int blk   = blockIdx.x;
    const int wave  = tid >> 6;             // 0..7
    const int lane  = tid & 63;
    const int chunk = (blk & 7) >> 1;       // XCD pair {2c, 2c+1}
    const int brow  = ((blk >> 3) << 1) | (blk & 1);   // 0..63
    const int R0    = brow * 32 + wave * 4;

    const float bias = (chunk & 1) ? 6.0f : 2.0f;
    // chunk 0: [0, 4288) no warm-up; chunk c>=1: g0 = 4288+(c-1)*4032-256
    const int g0 = (chunk == 0) ? 0 : (C0LEN + (chunk - 1) * CLEN - WUP);

    // W fragments: 4 rows x 8 float4 = 128 floats/lane, pinned.
    float4 wq[4][8];
#pragma unroll
    for (int r = 0; r < 4; ++r)
#pragma unroll
        for (int m = 0; m < 8; ++m) {
            wq[r][m] = *(const float4*)&W[(size_t)(R0 + r) * RR + 4 * lane + 256 * m];
            PIN4(wq[r][m]);
        }
    // Bias-fold: tw[r] = bias * sum of this lane's row-r fragment.
    float tw[4];
#pragma unroll
    for (int r = 0; r < 4; ++r) {
        float s = 0.f;
#pragma unroll
        for (int m = 0; m < 8; ++m)
            s += wq[r][m].x + wq[r][m].y + wq[r][m].z + wq[r][m].w;
        tw[r] = bias * s;
    }
    // Input projection fragments
    float win[4];
#pragma unroll
    for (int r = 0; r < 4; ++r)
        win[r] = Win[(size_t)(R0 + r) * II + lane];

    __shared__ float hbuf[2][RR];   // double-buffered biased h tile

    float hold = 0.f;               // lane tracks row R0 + (lane&3)
    float xv   = x[(size_t)g0 * II + lane];   // x pipeline: preload round 0

    for (int j = 0; j < NROUND; ++j) {
        const int g = g0 + j;
        float a0 = win[0] * xv;
        float a1 = win[1] * xv;
        float a2 = win[2] * xv;
        float a3 = win[3] * xv;
        float xn;                    // next round's x (no pin!)

        if (j > 0) {
            const float* hp = states + (size_t)(g - 1) * RR;
            float* sb = hbuf[(j - 1) & 1];
            // First pass: 4 coalesced dword poll loads per thread.
            float v0 = __hip_atomic_load(hp + tid,
                                         __ATOMIC_RELAXED, __HIP_MEMORY_SCOPE_AGENT);
            float v1 = __hip_atomic_load(hp + tid + 512,
                                         __ATOMIC_RELAXED, __HIP_MEMORY_SCOPE_AGENT);
            float v2 = __hip_atomic_load(hp + tid + 1024,
                                         __ATOMIC_RELAXED, __HIP_MEMORY_SCOPE_AGENT);
            float v3 = __hip_atomic_load(hp + tid + 1536,
                                         __ATOMIC_RELAXED, __HIP_MEMORY_SCOPE_AGENT);
            // Parity-range readiness: accept only my chunk's bias range.
            for (;;) {
                const bool r0 = fabsf(v0 - bias) <= 1.25f;
                const bool r1 = fabsf(v1 - bias) <= 1.25f;
                const bool r2 = fabsf(v2 - bias) <= 1.25f;
                const bool r3 = fabsf(v3 - bias) <= 1.25f;
                if (r0 && r1 && r2 && r3) break;
                if (!r0) v0 = __hip_atomic_load(hp + tid,
                                __ATOMIC_RELAXED, __HIP_MEMORY_SCOPE_AGENT);
                if (!r1) v1 = __hip_atomic_load(hp + tid + 512,
                                __ATOMIC_RELAXED, __HIP_MEMORY_SCOPE_AGENT);
                if (!r2) v2 = __hip_atomic_load(hp + tid + 1024,
                                __ATOMIC_RELAXED, __HIP_MEMORY_SCOPE_AGENT);
                if (!r3) v3 = __hip_atomic_load(hp + tid + 1536,
                                __ATOMIC_RELAXED, __HIP_MEMORY_SCOPE_AGENT);
            }
            // Publish raw biased values (stride-512: 2-way bank alias, free)
            sb[tid]        = v0;
            sb[tid + 512]  = v1;
            sb[tid + 1024] = v2;
            sb[tid + 1536] = v3;
            __syncthreads();           // the ONLY barrier per round

            // x pipeline: issue next round's x AFTER the barrier; its
            // latency hides under the LDS consume below.
            {
                const int gn = (g + 1 < SS) ? (g + 1) : (SS - 1);
                xn = x[(size_t)gn * II + lane];
            }

            a0 -= tw[0]; a1 -= tw[1]; a2 -= tw[2]; a3 -= tw[3];

            // Consume: 8 x ds_read_b128 vs register-held W (4 rows).
            const float4* sq = (const float4*)sb;
#pragma unroll
            for (int m = 0; m < 8; ++m) {
                const float4 q = sq[lane + 64 * m];
                a0 += wq[0][m].x * q.x + wq[0][m].y * q.y
                    + wq[0][m].z * q.z + wq[0][m].w * q.w;
                a1 += wq[1][m].x * q.x + wq[1][m].y * q.y
                    + wq[1][m].z * q.z + wq[1][m].w * q.w;
                a2 += wq[2][m].x * q.x + wq[2][m].y * q.y
                    + wq[2][m].z * q.z + wq[2][m].w * q.w;
                a3 += wq[3][m].x * q.x + wq[3][m].y * q.y
                    + wq[3][m].z * q.z + wq[3][m].w * q.w;
            }
        } else {
            xn = x[(size_t)(g0 + 1) * II + lane];
        }

        // Reduce 4 rows: 2 fold stages + 4-level butterfly (7 shfls).
        {
            const float own01 = (lane & 1) ? a1 : a0;
            const float oth01 = (lane & 1) ? a0 : a1;
            const float u01   = own01 + __shfl_xor(oth01, 1, 64);
            const float own23 = (lane & 1) ? a3 : a2;
            const float oth23 = (lane & 1) ? a2 : a3;
            const float u23   = own23 + __shfl_xor(oth23, 1, 64);
            const float own   = (lane & 2) ? u23 : u01;
            const float oth   = (lane & 2) ? u01 : u23;
            float a = own + __shfl_xor(oth, 2, 64);
#pragma unroll
            for (int off = 4; off <= 32; off <<= 1)
                a += __shfl_xor(a, off, 64);
            // tanh + leaky update for row R0 + (lane&3)
            float u = fminf(fmaxf(a, -20.f), 20.f);
            const float e  = __expf(2.f * u);
            const float th = (e - 1.f) / (e + 1.f);
            const float hn = 0.5f * hold + 0.5f * th;
            hold = hn;
            if (lane < 4)
                __hip_atomic_store(&states[(size_t)g * RR + R0 + lane], hn + bias,
                                   __ATOMIC_RELAXED, __HIP_MEMORY_SCOPE_AGENT);
        }

        xv = xn;                     // rotate x pipeline
    }
}

// ---------------------------------------------------------------------------
// rowsum of fc1_w rows: rs[h] = sum_r fc1_w[h][r]
// ---------------------------------------------------------------------------
__global__ void k_rowsum(const float* __restrict__ fc1w, float* __restrict__ rs)
{
    const int h = blockIdx.x;
    const int tid = threadIdx.x;
    float a = 0.f;
    for (int r = tid; r < RR; r += 256) a += fc1w[(size_t)h * RR + r];
#pragma unroll
    for (int off = 1; off <= 32; off <<= 1) a += __shfl_xor(a, off, 64);
    __shared__ float red[4];
    if ((tid & 63) == 0) red[tid >> 6] = a;
    __syncthreads();
    if (tid == 0) rs[h] = red[0] + red[1] + red[2] + red[3];
}

// ---------------------------------------------------------------------------
// Mt[r][o] = sum_h fc2_w[o][h] * fc1_w[h][r]   (o padded to 64, zeros)
// ---------------------------------------------------------------------------
__global__ void k_mt(const float* __restrict__ fc1w,
                     const float* __restrict__ fc2w,
                     float* __restrict__ Mt)
{
    __shared__ float w2[OO][HH + 1];
    const int o = threadIdx.x;         // 64
    const int r = blockIdx.x;          // 2048
    for (int i = o; i < OO * HH; i += 64) w2[i / HH][i % HH] = fc2w[i];
    __syncthreads();
    float a = 0.f;
    if (o < OO) {
        for (int h = 0; h < HH; ++h)
            a += w2[o][h] * fc1w[(size_t)h * RR + r];
    }
    Mt[r * OP + o] = a;
}

// ---------------------------------------------------------------------------
// c2b[o] = fc2_b[o] + sum_h fc2_w[o][h]*fc1_b[h];  rm[o] = sum_h fc2w*rs[h]
// ---------------------------------------------------------------------------
__global__ void k_cc(const float* __restrict__ fc2w,
                     const float* __restrict__ fc2b,
                     const float* __restrict__ fc1b,
                     const float* __restrict__ rs,
                     float* __restrict__ c2b,
                     float* __restrict__ rm)
{
    const int o = threadIdx.x;  // 64
    float a = 0.f, b = 0.f;
    if (o < OO) {
        for (int h = 0; h < HH; ++h) {
            a += fc2w[o * HH + h] * fc1b[h];
            b += fc2w[o * HH + h] * rs[h];
        }
        a += fc2b[o];
    }
    c2b[o] = a;
    rm[o]  = b;
}

// ---------------------------------------------------------------------------
// out[t][o] = sum_r Mt[r][o] * states_biased[t][r] + c2b[o] - bias_t*rm[o]
// Chunk boundaries 4288/8320/12352 are %16==0, so a 16-step tile is
// chunk-uniform.
// ---------------------------------------------------------------------------
__global__ __launch_bounds__(256)
void out_kernel(const float* __restrict__ sb,
                const float* __restrict__ Mt,
                const float* __restrict__ c2b,
                const float* __restrict__ rm,
                float* __restrict__ out)
{
    const int tid = threadIdx.x;
    const int o   = tid & 63;
    const int tl  = tid >> 6;          // 0..3
    const int t0  = blockIdx.x * TT;
    const int chunk = (t0 < C0LEN) ? 0 : (1 + (t0 - C0LEN) / CLEN);
    const float bias = (chunk & 1) ? 6.0f : 2.0f;
    float acc[4] = {0.f, 0.f, 0.f, 0.f};
    const float* s0 = sb + (size_t)t0 * RR;

    for (int r = 0; r < RR; r += 4) {
        float4 sv0 = *(const float4*)(s0 + (size_t)(tl + 0)  * RR + r);
        float4 sv1 = *(const float4*)(s0 + (size_t)(tl + 4)  * RR + r);
        float4 sv2 = *(const float4*)(s0 + (size_t)(tl + 8)  * RR + r);
        float4 sv3 = *(const float4*)(s0 + (size_t)(tl + 12) * RR + r);
        float m0 = Mt[(r + 0) * OP + o];
        float m1 = Mt[(r + 1) * OP + o];
        float m2 = Mt[(r + 2) * OP + o];
        float m3 = Mt[(r + 3) * OP + o];
        acc[0] += m0 * sv0.x + m1 * sv0.y + m2 * sv0.z + m3 * sv0.w;
        acc[1] += m0 * sv1.x + m1 * sv1.y + m2 * sv1.z + m3 * sv1.w;
        acc[2] += m0 * sv2.x + m1 * sv2.y + m2 * sv2.z + m3 * sv2.w;
        acc[3] += m0 * sv3.x + m1 * sv3.y + m2 * sv3.z + m3 * sv3.w;
    }
    if (o < OO) {
        const float cc = c2b[o] - bias * rm[o];
#pragma unroll
        for (int m = 0; m < 4; ++m) {
            const int t = t0 + tl + 4 * m;
            out[(size_t)t * OO + o] = acc[m] + cc;
        }
    }
}

extern "C" void kernel_launch(void* const* d_in, const int* in_sizes, int n_in,
                              void* d_out, int out_size, void* d_ws, size_t ws_size,
                              hipStream_t stream)
{
    const float* x    = (const float*)d_in[0];
    const float* Win  = (const float*)d_in[1];
    const float* W    = (const float*)d_in[2];
    const float* fc1w = (const float*)d_in[3];
    const float* fc1b = (const float*)d_in[4];
    const float* fc2w = (const float*)d_in[5];
    const float* fc2b = (const float*)d_in[6];
    float* out = (float*)d_out;

    if (ws_size < WS_NEED) return;

    char*  ws     = (char*)d_ws;
    float* states = (float*)ws;
    float* Mt     = (float*)(ws + MT_OFF);
    float* c2b    = (float*)(ws + C2B_OFF);
    float* rm     = (float*)(ws + RM_OFF);
    float* rs     = (float*)(ws + RS_OFF);

    // Sentinel init: 0.0f is outside both bias ranges -> "not ready".
    hipMemsetAsync(states, 0, STATES_BYTES, stream);

    k_rowsum<<<HH, 256, 0, stream>>>(fc1w, rs);
    k_mt<<<RR, 64, 0, stream>>>(fc1w, fc2w, Mt);
    k_cc<<<1, 64, 0, stream>>>(fc2w, fc2b, fc1b, rs, c2b, rm);

    scan_kernel<<<NBLK, NTHR, 0, stream>>>(x, Win, W, states);

    out_kernel<<<SS / TT, 256, 0, stream>>>(states, Mt, c2b, rm, out);
}

// Round 16
// 6488.269 us; speedup vs baseline: 1.3485x; 1.3485x over previous
//
#include <hip/hip_runtime.h>
#include <math.h>

// Echo-state network: sequential scan with dense 2048x2048 matvec per step.
// R16 -- R14's proven structure (x load IN-LOOP), warm-up 256 -> 64:
//  - R15 lesson (3rd confirmation of the family: R6 pin, R15 carry): any
//    VMEM-dependent value carried across the back-edge forces a waitcnt
//    drain (incl. the h-store ack) BEFORE the poll issue -> +0.5us/round.
//    The R14 in-loop x load drains together with the poll loads -- optimal.
//  - Warm-up 64: contraction lambda ~0.85-0.87/step -> lambda^64 ~ 3e-5
//    attenuation; absmax was bit-identical at WUP=1024 and 256, so margin
//    is enormous. Uneven chunks equalize finish: chunk0 = 4144 outputs,
//    chunks1-3 = 4080 + 64 warm-up -> uniform 4144 rounds.
//    Boundaries 4144/8224/12304 (all %16==0 for out_kernel tiles).
//  - Register-pool arithmetic: ~236 regs/wave -> exactly 2 waves/SIMD;
//    4 chunks is the hard cap for W-in-register replication.
//  - XCD-affinity remap: chunk = (blk&7)>>1 -> chunk's 64 blocks on XCD pair
//    {2c,2c+1} under blockIdx%8 round-robin dispatch (R14, kept).
//  - Parity bias-tag: even chunks store h+2, odd h+6; poll accepts
//    |v-bias|<=1.25; memset-0 / 0xAA poison read not-ready. Warm-up writes
//    of chunk c+1 trail chunk c's true writes by ~4000 lockstep rounds.
//  - Per-round machinery = R5/R11: block-cooperative poll (4 dwords/thr),
//    straggler-only retry, publish to LDS, ONE barrier, consume
//    8 x ds_read_b128 vs register W, 7-shfl reduce, tanh, store.
//  - fc1/fc2 collapse: out = states_biased @ Mt + (c2b - bias_t * rm).

#define SS 16384
#define II 64
#define RR 2048
#define HH 128
#define OO 50
#define OP 64          // padded output dim
#define NROUND 4144    // rounds per chunk (uniform)
#define C0LEN 4144     // chunk 0 output length
#define CLEN 4080      // chunks 1-3 output length
#define WUP 64         // warm-up steps for chunks 1-3
#define NBLK 256
#define NTHR 512
#define TT 16          // timesteps per block in out_kernel

static const size_t STATES_BYTES = (size_t)SS * RR * 4;        // 134217728
static const size_t MT_OFF  = STATES_BYTES;
static const size_t C2B_OFF = MT_OFF + (size_t)RR * OP * 4;    // +524288
static const size_t RM_OFF  = C2B_OFF + 256;
static const size_t RS_OFF  = RM_OFF + 256;
static const size_t WS_NEED = RS_OFF + 512 + 256;

// Opaque register pin for LOOP-INVARIANT values (W fragments) only.
// NEVER on in-loop load results (forces a waitcnt at the pin site -- R6/R15).
#define PIN4(q) asm volatile("" : "+v"((q).x), "+v"((q).y), "+v"((q).z), "+v"((q).w))

// ---------------------------------------------------------------------------
// Persistent chunked scan. chunk = (blk&7)>>1 (XCD-pair affinity),
// brow = (blk>>3)*2 + (blk&1). Wave w owns rows R0=brow*32+w*4 .. R0+3;
// lane l holds cols {4l+j+256m} of its 4 rows.
// ---------------------------------------------------------------------------
__global__ __launch_bounds__(NTHR, 2)
void scan_kernel(const float* __restrict__ x,
                 const float* __restrict__ Win,
                 const float* __restrict__ W,
                 float* __restrict__ states)
{
    const int tid   = threadIdx.x;
    const int blk   = blockIdx.x;
    const int wave  = tid >> 6;             // 0..7
    const int lane  = tid & 63;
    const int chunk = (blk & 7) >> 1;       // XCD pair {2c, 2c+1}
    const int brow  = ((blk >> 3) << 1) | (blk & 1);   // 0..63
    const int R0    = brow * 32 + wave * 4;

    const float bias = (chunk & 1) ? 6.0f : 2.0f;
    // chunk 0: [0, 4144) no warm-up; chunk c>=1: g0 = 4144+(c-1)*4080-64
    const int g0 = (chunk == 0) ? 0 : (C0LEN + (chunk - 1) * CLEN - WUP);

    // W fragments: 4 rows x 8 float4 = 128 floats/lane, pinned.
    float4 wq[4][8];
#pragma unroll
    for (int r = 0; r < 4; ++r)
#pragma unroll
        for (int m = 0; m < 8; ++m) {
            wq[r][m] = *(const float4*)&W[(size_t)(R0 + r) * RR + 4 * lane + 256 * m];
            PIN4(wq[r][m]);
        }
    // Bias-fold: tw[r] = bias * sum of this lane's row-r fragment.
    float tw[4];
#pragma unroll
    for (int r = 0; r < 4; ++r) {
        float s = 0.f;
#pragma unroll
        for (int m = 0; m < 8; ++m)
            s += wq[r][m].x + wq[r][m].y + wq[r][m].z + wq[r][m].w;
        tw[r] = bias * s;
    }
    // Input projection fragments
    float win[4];
#pragma unroll
    for (int r = 0; r < 4; ++r)
        win[r] = Win[(size_t)(R0 + r) * II + lane];

    __shared__ float hbuf[2][RR];   // double-buffered biased h tile

    float hold = 0.f;               // lane tracks row R0 + (lane&3)

    for (int j = 0; j < NROUND; ++j) {
        const int g = g0 + j;
        const float xv = x[(size_t)g * II + lane];  // in-loop: drains with poll
        float a0 = win[0] * xv;
        float a1 = win[1] * xv;
        float a2 = win[2] * xv;
        float a3 = win[3] * xv;

        if (j > 0) {
            const float* hp = states + (size_t)(g - 1) * RR;
            float* sb = hbuf[(j - 1) & 1];
            // First pass: 4 coalesced dword poll loads per thread.
            float v0 = __hip_atomic_load(hp + tid,
                                         __ATOMIC_RELAXED, __HIP_MEMORY_SCOPE_AGENT);
            float v1 = __hip_atomic_load(hp + tid + 512,
                                         __ATOMIC_RELAXED, __HIP_MEMORY_SCOPE_AGENT);
            float v2 = __hip_atomic_load(hp + tid + 1024,
                                         __ATOMIC_RELAXED, __HIP_MEMORY_SCOPE_AGENT);
            float v3 = __hip_atomic_load(hp + tid + 1536,
                                         __ATOMIC_RELAXED, __HIP_MEMORY_SCOPE_AGENT);
            // Parity-range readiness: accept only my chunk's bias range.
            for (;;) {
                const bool r0 = fabsf(v0 - bias) <= 1.25f;
                const bool r1 = fabsf(v1 - bias) <= 1.25f;
                const bool r2 = fabsf(v2 - bias) <= 1.25f;
                const bool r3 = fabsf(v3 - bias) <= 1.25f;
                if (r0 && r1 && r2 && r3) break;
                if (!r0) v0 = __hip_atomic_load(hp + tid,
                                __ATOMIC_RELAXED, __HIP_MEMORY_SCOPE_AGENT);
                if (!r1) v1 = __hip_atomic_load(hp + tid + 512,
                                __ATOMIC_RELAXED, __HIP_MEMORY_SCOPE_AGENT);
                if (!r2) v2 = __hip_atomic_load(hp + tid + 1024,
                                __ATOMIC_RELAXED, __HIP_MEMORY_SCOPE_AGENT);
                if (!r3) v3 = __hip_atomic_load(hp + tid + 1536,
                                __ATOMIC_RELAXED, __HIP_MEMORY_SCOPE_AGENT);
            }
            // Publish raw biased values (stride-512: 2-way bank alias, free)
            sb[tid]        = v0;
            sb[tid + 512]  = v1;
            sb[tid + 1024] = v2;
            sb[tid + 1536] = v3;
            __syncthreads();           // the ONLY barrier per round

            a0 -= tw[0]; a1 -= tw[1]; a2 -= tw[2]; a3 -= tw[3];

            // Consume: 8 x ds_read_b128 vs register-held W (4 rows).
            const float4* sq = (const float4*)sb;
#pragma unroll
            for (int m = 0; m < 8; ++m) {
                const float4 q = sq[lane + 64 * m];
                a0 += wq[0][m].x * q.x + wq[0][m].y * q.y
                    + wq[0][m].z * q.z + wq[0][m].w * q.w;
                a1 += wq[1][m].x * q.x + wq[1][m].y * q.y
                    + wq[1][m].z * q.z + wq[1][m].w * q.w;
                a2 += wq[2][m].x * q.x + wq[2][m].y * q.y
                    + wq[2][m].z * q.z + wq[2][m].w * q.w;
                a3 += wq[3][m].x * q.x + wq[3][m].y * q.y
                    + wq[3][m].z * q.z + wq[3][m].w * q.w;
            }
        }

        // Reduce 4 rows: 2 fold stages + 4-level butterfly (7 shfls).
        {
            const float own01 = (lane & 1) ? a1 : a0;
            const float oth01 = (lane & 1) ? a0 : a1;
            const float u01   = own01 + __shfl_xor(oth01, 1, 64);
            const float own23 = (lane & 1) ? a3 : a2;
            const float oth23 = (lane & 1) ? a2 : a3;
            const float u23   = own23 + __shfl_xor(oth23, 1, 64);
            const float own   = (lane & 2) ? u23 : u01;
            const float oth   = (lane & 2) ? u01 : u23;
            float a = own + __shfl_xor(oth, 2, 64);
#pragma unroll
            for (int off = 4; off <= 32; off <<= 1)
                a += __shfl_xor(a, off, 64);
            // tanh + leaky update for row R0 + (lane&3)
            float u = fminf(fmaxf(a, -20.f), 20.f);
            const float e  = __expf(2.f * u);
            const float th = (e - 1.f) / (e + 1.f);
            const float hn = 0.5f * hold + 0.5f * th;
            hold = hn;
            if (lane < 4)
                __hip_atomic_store(&states[(size_t)g * RR + R0 + lane], hn + bias,
                                   __ATOMIC_RELAXED, __HIP_MEMORY_SCOPE_AGENT);
        }
    }
}

// ---------------------------------------------------------------------------
// rowsum of fc1_w rows: rs[h] = sum_r fc1_w[h][r]
// ---------------------------------------------------------------------------
__global__ void k_rowsum(const float* __restrict__ fc1w, float* __restrict__ rs)
{
    const int h = blockIdx.x;
    const int tid = threadIdx.x;
    float a = 0.f;
    for (int r = tid; r < RR; r += 256) a += fc1w[(size_t)h * RR + r];
#pragma unroll
    for (int off = 1; off <= 32; off <<= 1) a += __shfl_xor(a, off, 64);
    __shared__ float red[4];
    if ((tid & 63) == 0) red[tid >> 6] = a;
    __syncthreads();
    if (tid == 0) rs[h] = red[0] + red[1] + red[2] + red[3];
}

// ---------------------------------------------------------------------------
// Mt[r][o] = sum_h fc2_w[o][h] * fc1_w[h][r]   (o padded to 64, zeros)
// ---------------------------------------------------------------------------
__global__ void k_mt(const float* __restrict__ fc1w,
                     const float* __restrict__ fc2w,
                     float* __restrict__ Mt)
{
    __shared__ float w2[OO][HH + 1];
    const int o = threadIdx.x;         // 64
    const int r = blockIdx.x;          // 2048
    for (int i = o; i < OO * HH; i += 64) w2[i / HH][i % HH] = fc2w[i];
    __syncthreads();
    float a = 0.f;
    if (o < OO) {
        for (int h = 0; h < HH; ++h)
            a += w2[o][h] * fc1w[(size_t)h * RR + r];
    }
    Mt[r * OP + o] = a;
}

// ---------------------------------------------------------------------------
// c2b[o] = fc2_b[o] + sum_h fc2_w[o][h]*fc1_b[h];  rm[o] = sum_h fc2w*rs[h]
// ---------------------------------------------------------------------------
__global__ void k_cc(const float* __restrict__ fc2w,
                     const float* __restrict__ fc2b,
                     const float* __restrict__ fc1b,
                     const float* __restrict__ rs,
                     float* __restrict__ c2b,
                     float* __restrict__ rm)
{
    const int o = threadIdx.x;  // 64
    float a = 0.f, b = 0.f;
    if (o < OO) {
        for (int h = 0; h < HH; ++h) {
            a += fc2w[o * HH + h] * fc1b[h];
            b += fc2w[o * HH + h] * rs[h];
        }
        a += fc2b[o];
    }
    c2b[o] = a;
    rm[o]  = b;
}

// ---------------------------------------------------------------------------
// out[t][o] = sum_r Mt[r][o] * states_biased[t][r] + c2b[o] - bias_t*rm[o]
// Chunk boundaries 4144/8224/12304 are %16==0, so a 16-step tile is
// chunk-uniform.
// ---------------------------------------------------------------------------
__global__ __launch_bounds__(256)
void out_kernel(const float* __restrict__ sb,
                const float* __restrict__ Mt,
                const float* __restrict__ c2b,
                const float* __restrict__ rm,
                float* __restrict__ out)
{
    const int tid = threadIdx.x;
    const int o   = tid & 63;
    const int tl  = tid >> 6;          // 0..3
    const int t0  = blockIdx.x * TT;
    const int chunk = (t0 < C0LEN) ? 0 : (1 + (t0 - C0LEN) / CLEN);
    const float bias = (chunk & 1) ? 6.0f : 2.0f;
    float acc[4] = {0.f, 0.f, 0.f, 0.f};
    const float* s0 = sb + (size_t)t0 * RR;

    for (int r = 0; r < RR; r += 4) {
        float4 sv0 = *(const float4*)(s0 + (size_t)(tl + 0)  * RR + r);
        float4 sv1 = *(const float4*)(s0 + (size_t)(tl + 4)  * RR + r);
        float4 sv2 = *(const float4*)(s0 + (size_t)(tl + 8)  * RR + r);
        float4 sv3 = *(const float4*)(s0 + (size_t)(tl + 12) * RR + r);
        float m0 = Mt[(r + 0) * OP + o];
        float m1 = Mt[(r + 1) * OP + o];
        float m2 = Mt[(r + 2) * OP + o];
        float m3 = Mt[(r + 3) * OP + o];
        acc[0] += m0 * sv0.x + m1 * sv0.y + m2 * sv0.z + m3 * sv0.w;
        acc[1] += m0 * sv1.x + m1 * sv1.y + m2 * sv1.z + m3 * sv1.w;
        acc[2] += m0 * sv2.x + m1 * sv2.y + m2 * sv2.z + m3 * sv2.w;
        acc[3] += m0 * sv3.x + m1 * sv3.y + m2 * sv3.z + m3 * sv3.w;
    }
    if (o < OO) {
        const float cc = c2b[o] - bias * rm[o];
#pragma unroll
        for (int m = 0; m < 4; ++m) {
            const int t = t0 + tl + 4 * m;
            out[(size_t)t * OO + o] = acc[m] + cc;
        }
    }
}

extern "C" void kernel_launch(void* const* d_in, const int* in_sizes, int n_in,
                              void* d_out, int out_size, void* d_ws, size_t ws_size,
                              hipStream_t stream)
{
    const float* x    = (const float*)d_in[0];
    const float* Win  = (const float*)d_in[1];
    const float* W    = (const float*)d_in[2];
    const float* fc1w = (const float*)d_in[3];
    const float* fc1b = (const float*)d_in[4];
    const float* fc2w = (const float*)d_in[5];
    const float* fc2b = (const float*)d_in[6];
    float* out = (float*)d_out;

    if (ws_size < WS_NEED) return;

    char*  ws     = (char*)d_ws;
    float* states = (float*)ws;
    float* Mt     = (float*)(ws + MT_OFF);
    float* c2b    = (float*)(ws + C2B_OFF);
    float* rm     = (float*)(ws + RM_OFF);
    float* rs     = (float*)(ws + RS_OFF);

    // Sentinel init: 0.0f is outside both bias ranges -> "not ready".
    hipMemsetAsync(states, 0, STATES_BYTES, stream);

    k_rowsum<<<HH, 256, 0, stream>>>(fc1w, rs);
    k_mt<<<RR, 64, 0, stream>>>(fc1w, fc2w, Mt);
    k_cc<<<1, 64, 0, stream>>>(fc2w, fc2b, fc1b, rs, c2b, rm);

    scan_kernel<<<NBLK, NTHR, 0, stream>>>(x, Win, W, states);

    out_kernel<<<SS / TT, 256, 0, stream>>>(states, Mt, c2b, rm, out);
}